// Round 7
// baseline (731.694 us; speedup 1.0000x reference)
//
#include <hip/hip_runtime.h>
#include <hip/hip_bf16.h>
#include <hip/hip_cooperative_groups.h>

namespace cg = cooperative_groups;

typedef __attribute__((ext_vector_type(8))) short short8;
typedef __attribute__((ext_vector_type(4))) float floatx4;
typedef __attribute__((ext_vector_type(2))) float float2v;

__device__ __forceinline__ float leaky(float v){ return v > 0.f ? v : 0.1f*v; }
__device__ __forceinline__ void atomAdd(float* p, float v){ unsafeAtomicAdd(p, v); }
__device__ __forceinline__ short f2bf(float f){
  __hip_bfloat16 h = __float2bfloat16(f);
  return *reinterpret_cast<short*>(&h);
}

struct MegaP {
  const float *x; const int *ei; const int *batch;
  const float *en1_w1,*en1_b1,*en1_w2,*en1_b2;
  const float *en2_w1,*en2_b1,*en2_w2,*en2_b2;
  const float *en3_w1,*en3_b1,*en3_w2,*en3_b2;
  const float *root1,*cb1,*root2,*cb2,*root3,*cb3;
  const float *fc1w,*fc1b,*fc2w,*fc2b,*fc3w,*fc3b;
  short *ef2b,*ef3b,*w2p2,*w2p3;
  float *a1,*a2,*a3,*g,*out;
  int N,E,Epad;
};

struct SMem {
  union {
    struct { float hsT[32*64]; int sdst[64]; } c3;                       // 8704 B
    struct { float hsT[8*32];  int sdst[32]; } c2;                       // 1152 B
    struct { float rootS[8192]; float hrow[16][64]; } np;                // 36864 B
    struct { float w1s[3][192]; float b1s[3][64]; float c1w2s[2048];
             float c1b2s[32]; float sm[4][64]; } ef;                     // 12416 B
    struct { float s1[128]; float s2[128]; } hd;                         // 1024 B
  };
};

// One NNConv edge-tile unit (proven conv_mfma body, ping-pong B, pk epilogue).
template<int IC, int OC, int MB, int ICB>
__device__ __forceinline__ void conv_unit(float* hsT, int* sdst,
    const short* __restrict__ efb, const float* __restrict__ h,
    const int* __restrict__ ei, const short* __restrict__ w2p,
    const float* __restrict__ b2, float* __restrict__ agg,
    int E, int eb, int i0){
  constexpr int ME = MB*16, OT = OC/16, WOT = OT/4;
  int tid = threadIdx.x;
  { // stage h[src, i0:i0+ICB] transposed
    int e = tid % ME;
    int ge = eb + e;
    bool valid = ge < E;
    int src = valid ? ei[ge] : 0;
    constexpr int CH = 256/ME, IPC = ICB/CH;
    int c = tid / ME;
    const float* hp = h + (size_t)src*IC + i0 + c*IPC;
    if constexpr (IPC == 8){
      #pragma unroll
      for (int half=0; half<2; half++){
        float4 hv = valid ? reinterpret_cast<const float4*>(hp)[half]
                          : float4{0.f,0.f,0.f,0.f};
        hsT[(c*IPC+half*4+0)*ME + e] = hv.x;
        hsT[(c*IPC+half*4+1)*ME + e] = hv.y;
        hsT[(c*IPC+half*4+2)*ME + e] = hv.z;
        hsT[(c*IPC+half*4+3)*ME + e] = hv.w;
      }
    } else {
      #pragma unroll
      for (int j=0;j<IPC;j++)
        hsT[(c*IPC+j)*ME + e] = valid ? hp[j] : 0.f;
    }
    if (tid < ME) sdst[tid] = (eb + tid < E) ? ei[E + eb + tid] : -1;
  }
  __syncthreads();

  int lane = tid & 63, wv = tid >> 6;
  int n = lane & 15, quad = lane >> 4;
  int o0 = wv * (OC/4);

  short8 A[MB][2];
  #pragma unroll
  for (int m=0;m<MB;m++)
    #pragma unroll
    for (int kh=0;kh<2;kh++)
      A[m][kh] = *reinterpret_cast<const short8*>(efb + (size_t)(eb + m*16 + n)*64 + kh*32 + quad*8);

  float2v msg[MB][WOT][2];
  #pragma unroll
  for (int m=0;m<MB;m++)
    #pragma unroll
    for (int t=0;t<WOT;t++){
      msg[m][t][0] = (float2v){0.f,0.f};
      msg[m][t][1] = (float2v){0.f,0.f};
    }

  auto loadB = [&](int ii, short8 (&Bt)[WOT][2], float (&bzt)[WOT]){
    int il = (ii < ICB) ? ii : (ICB-1);       // clamp prefetch overrun (unused values)
    int ig = i0 + il;
    #pragma unroll
    for (int t=0;t<WOT;t++){
      int otg = (o0 >> 4) + t;
      #pragma unroll
      for (int kh=0;kh<2;kh++)
        Bt[t][kh] = *reinterpret_cast<const short8*>(w2p + ((size_t)((ig*OT + otg)*2 + kh) << 9) + lane*8);
      bzt[t] = b2[ig*OC + o0 + t*16 + n];
    }
  };
  auto compute = [&](int ii, short8 (&Bt)[WOT][2], float (&bzt)[WOT]){
    #pragma unroll
    for (int m=0;m<MB;m++){
      float4 hv = *reinterpret_cast<const float4*>(&hsT[ii*ME + m*16 + quad*4]);
      float2v hvl = {hv.x, hv.y};
      float2v hvh = {hv.z, hv.w};
      #pragma unroll
      for (int t=0;t<WOT;t++){
        floatx4 z = {bzt[t], bzt[t], bzt[t], bzt[t]};
        z = __builtin_amdgcn_mfma_f32_16x16x32_bf16(A[m][0], Bt[t][0], z, 0, 0, 0);
        z = __builtin_amdgcn_mfma_f32_16x16x32_bf16(A[m][1], Bt[t][1], z, 0, 0, 0);
        float2v zl = {z[0], z[1]};
        float2v zh = {z[2], z[3]};
        float2v ll = __builtin_elementwise_max(zl, zl*0.1f);
        float2v lh = __builtin_elementwise_max(zh, zh*0.1f);
        msg[m][t][0] += hvl*ll;
        msg[m][t][1] += hvh*lh;
      }
    }
  };

  short8 B0[WOT][2], B1[WOT][2];
  float bz0[WOT], bz1[WOT];
  loadB(0, B0, bz0);
  #pragma unroll 2
  for (int i=0;i<ICB;i+=2){
    loadB(i+1, B1, bz1);
    compute(i, B0, bz0);
    loadB(i+2, B0, bz0);
    compute(i+1, B1, bz1);
  }

  #pragma unroll
  for (int m=0;m<MB;m++){
    #pragma unroll
    for (int r=0;r<4;r++){
      int d = sdst[m*16 + quad*4 + r];
      if (d >= 0){
        #pragma unroll
        for (int t=0;t<WOT;t++)
          atomAdd(&agg[(size_t)d*OC + o0 + t*16 + n], msg[m][t][r>>1][r&1]);
      }
    }
  }
  __syncthreads();  // protect hsT/sdst for next unit
}

__global__ __launch_bounds__(256, 4) void mega(MegaP p){
  cg::grid_group grid = cg::this_grid();
  __shared__ SMem S;
  const int tid = threadIdx.x, bid = blockIdx.x, nb = gridDim.x;
  const int N = p.N, E = p.E, Epad = p.Epad;

  // ---- Phase 0: zero agg buffers + pack w2 matrices into MFMA B-fragment order ----
  {
    size_t zn = (size_t)N*(8+64+128) + 32*128;
    for (size_t i = (size_t)bid*256 + tid; i < zn; i += (size_t)nb*256) p.a1[i] = 0.f;
    for (int t = bid*256 + tid; t < 1088*64; t += nb*256){
      int lane = t & 63, c = t >> 6;
      const float* w2; short* dst; int ICOC, OT, cc;
      if (c < 64){ w2 = p.en2_w2; dst = p.w2p2; ICOC = 512;  OT = 4; cc = c; }
      else       { w2 = p.en3_w2; dst = p.w2p3; ICOC = 8192; OT = 8; cc = c - 64; }
      int kh = cc & 1, rem = cc >> 1, otg = rem % OT, i = rem / OT;
      int n = lane & 15, q = lane >> 4;
      short o8[8];
      #pragma unroll
      for (int j=0;j<8;j++){
        int k = kh*32 + q*8 + j;
        o8[j] = f2bf(w2[(size_t)k*ICOC + i*(OT*16) + otg*16 + n]);
      }
      *reinterpret_cast<short8*>(dst + (size_t)cc*512 + lane*8) = *reinterpret_cast<short8*>(o8);
    }
  }
  grid.sync();

  // ---- Phase 1: edge features (3 nets) + conv1 message pass ----
  {
    for (int idx = tid; idx < 576; idx += 256){
      int net = idx / 192, r = idx % 192;
      S.ef.w1s[net][r] = (net==0 ? p.en1_w1 : net==1 ? p.en2_w1 : p.en3_w1)[r];
    }
    if (tid < 192){
      int net = tid >> 6, j = tid & 63;
      S.ef.b1s[net][j] = (net==0 ? p.en1_b1 : net==1 ? p.en2_b1 : p.en3_b1)[j];
    }
    for (int idx = tid; idx < 2048; idx += 256) S.ef.c1w2s[idx] = p.en1_w2[idx];
    if (tid < 32) S.ef.c1b2s[tid] = p.en1_b2[tid];
    __syncthreads();
    int nunits = Epad/4;
    for (int u = bid; u < nunits; u += nb){
      int e = u*4 + (tid >> 6), j = tid & 63;
      float v1 = 0.f;
      if (e >= E){
        p.ef2b[(size_t)e*64 + j] = 0; p.ef3b[(size_t)e*64 + j] = 0;
      } else {
        int s = p.ei[e], d = p.ei[E+e];
        float4 xs = *reinterpret_cast<const float4*>(p.x + (size_t)s*4);
        float4 xd = *reinterpret_cast<const float4*>(p.x + (size_t)d*4);
        float d0 = xd.y - xs.y, d1 = xd.z - xs.z, d2 = xd.w - xs.w;
        v1 = leaky(d0*S.ef.w1s[0][j] + d1*S.ef.w1s[0][64+j] + d2*S.ef.w1s[0][128+j] + S.ef.b1s[0][j]);
        p.ef2b[(size_t)e*64+j] = f2bf(leaky(d0*S.ef.w1s[1][j] + d1*S.ef.w1s[1][64+j] + d2*S.ef.w1s[1][128+j] + S.ef.b1s[1][j]));
        p.ef3b[(size_t)e*64+j] = f2bf(leaky(d0*S.ef.w1s[2][j] + d1*S.ef.w1s[2][64+j] + d2*S.ef.w1s[2][128+j] + S.ef.b1s[2][j]));
      }
      S.ef.sm[tid >> 6][j] = v1;
      __syncthreads();
      if (tid < 32){
        int le = tid >> 3, o = tid & 7;
        int ge = u*4 + le;
        if (ge < E){
          int s = p.ei[ge], d = p.ei[E+ge];
          float z[4];
          #pragma unroll
          for (int i=0;i<4;i++) z[i] = S.ef.c1b2s[i*8+o];
          for (int k=0;k<64;k++){
            float a = S.ef.sm[le][k];
            #pragma unroll
            for (int i=0;i<4;i++) z[i] += a*S.ef.c1w2s[k*32 + i*8 + o];
          }
          float4 xv = *reinterpret_cast<const float4*>(p.x + (size_t)s*4);
          float msg = xv.x*leaky(z[0]) + xv.y*leaky(z[1]) + xv.z*leaky(z[2]) + xv.w*leaky(z[3]);
          atomAdd(&p.a1[(size_t)d*8 + o], msg);
        }
      }
      __syncthreads();
    }
  }
  grid.sync();

  // ---- Phase 2: node1 ----
  for (int id = bid*256 + tid; id < N*8; id += nb*256){
    int nn = id >> 3, o = id & 7;
    float v = p.a1[id] + p.cb1[o];
    float4 xv = *reinterpret_cast<const float4*>(p.x + (size_t)nn*4);
    v += xv.x*p.root1[o] + xv.y*p.root1[8+o] + xv.z*p.root1[16+o] + xv.w*p.root1[24+o];
    p.a1[id] = leaky(v);
  }
  grid.sync();

  // ---- Phase 3: conv2 ----
  {
    int nunits = Epad/32;
    for (int u = bid; u < nunits; u += nb)
      conv_unit<8,64,2,8>(S.c2.hsT, S.c2.sdst, p.ef2b, p.a1, p.ei, p.w2p2, p.en2_b2, p.a2, E, u*32, 0);
  }
  grid.sync();

  // ---- Phase 4: node2 (vectorized x4) ----
  for (int id = bid*256 + tid; id < N*16; id += nb*256){
    int nn = id >> 4, o0 = (id & 15)*4;
    const float* hi = p.a1 + (size_t)nn*8;
    float4 v  = *reinterpret_cast<float4*>(p.a2 + (size_t)nn*64 + o0);
    float4 cbv = *reinterpret_cast<const float4*>(p.cb2 + o0);
    v.x += cbv.x; v.y += cbv.y; v.z += cbv.z; v.w += cbv.w;
    #pragma unroll
    for (int i=0;i<8;i++){
      float hv = hi[i];
      float4 rv = *reinterpret_cast<const float4*>(p.root2 + i*64 + o0);
      v.x += hv*rv.x; v.y += hv*rv.y; v.z += hv*rv.z; v.w += hv*rv.w;
    }
    v.x = leaky(v.x); v.y = leaky(v.y); v.z = leaky(v.z); v.w = leaky(v.w);
    *reinterpret_cast<float4*>(p.a2 + (size_t)nn*64 + o0) = v;
  }
  grid.sync();

  // ---- Phase 5: conv3 (2-way ic-split) ----
  {
    int nunits = (Epad/64)*2;
    for (int u = bid; u < nunits; u += nb)
      conv_unit<64,128,4,32>(S.c3.hsT, S.c3.sdst, p.ef3b, p.a2, p.ei, p.w2p3, p.en3_b2, p.a3, E, (u>>1)*64, (u&1)*32);
  }
  grid.sync();

  // ---- Phase 6: node3 + pool ----
  {
    for (int r = tid; r < 2048; r += 256)
      reinterpret_cast<float4*>(S.np.rootS)[r] = reinterpret_cast<const float4*>(p.root3)[r];
    __syncthreads();
    int nunits = (N + 15)/16;
    for (int u = bid; u < nunits; u += nb){
      int n0 = u*16;
      {
        int nn = tid >> 4, c = (tid & 15)*4;
        int n = n0 + nn;
        float4 hv = (n < N) ? *reinterpret_cast<const float4*>(p.a2 + (size_t)n*64 + c)
                            : float4{0.f,0.f,0.f,0.f};
        S.np.hrow[nn][c+0]=hv.x; S.np.hrow[nn][c+1]=hv.y; S.np.hrow[nn][c+2]=hv.z; S.np.hrow[nn][c+3]=hv.w;
      }
      __syncthreads();
      int o = tid & 127, np_ = tid >> 7;
      float acc = 0.f; int cur = -1;
      for (int rep=0; rep<8; rep++){
        int nl = rep*2 + np_; int n = n0 + nl;
        if (n >= N) break;
        int b = p.batch[n];
        if (b != cur){ if (cur >= 0) atomAdd(&p.g[cur*128+o], acc); acc = 0.f; cur = b; }
        float v = p.a3[(size_t)n*128 + o] + p.cb3[o];
        #pragma unroll 16
        for (int i=0;i<64;i++) v += S.np.hrow[nl][i]*S.np.rootS[i*128+o];
        acc += leaky(v);
      }
      if (cur >= 0) atomAdd(&p.g[cur*128+o], acc);
      __syncthreads();
    }
  }
  grid.sync();

  // ---- Phase 7: readout MLP ----
  if (bid < 32){
    int t = tid;
    if (t < 128) S.hd.s1[t] = p.g[bid*128 + t];
    __syncthreads();
    if (t < 128){
      float v = p.fc1b[t];
      for (int i=0;i<128;i++) v += S.hd.s1[i]*p.fc1w[i*128+t];
      S.hd.s2[t] = leaky(v);
    }
    __syncthreads();
    if (t < 64){
      float v2 = p.fc2b[t];
      for (int i=0;i<128;i++) v2 += S.hd.s2[i]*p.fc2w[i*64+t];
      S.hd.s1[t] = leaky(v2);
    }
    __syncthreads();
    if (t == 0){
      float v3 = p.fc3b[0];
      for (int i=0;i<64;i++) v3 += S.hd.s1[i]*p.fc3w[i];
      p.out[bid] = v3;
    }
  }
}

extern "C" void kernel_launch(void* const* d_in, const int* in_sizes, int n_in,
                              void* d_out, int out_size, void* d_ws, size_t ws_size,
                              hipStream_t stream) {
  MegaP prm;
  prm.x      = (const float*)d_in[0];
  prm.ei     = (const int*)  d_in[1];
  prm.batch  = (const int*)  d_in[2];
  prm.en1_w1 = (const float*)d_in[3];  prm.en1_b1 = (const float*)d_in[4];
  prm.en1_w2 = (const float*)d_in[5];  prm.en1_b2 = (const float*)d_in[6];
  prm.en2_w1 = (const float*)d_in[7];  prm.en2_b1 = (const float*)d_in[8];
  prm.en2_w2 = (const float*)d_in[9];  prm.en2_b2 = (const float*)d_in[10];
  prm.en3_w1 = (const float*)d_in[11]; prm.en3_b1 = (const float*)d_in[12];
  prm.en3_w2 = (const float*)d_in[13]; prm.en3_b2 = (const float*)d_in[14];
  prm.root1  = (const float*)d_in[15]; prm.cb1    = (const float*)d_in[16];
  prm.root2  = (const float*)d_in[17]; prm.cb2    = (const float*)d_in[18];
  prm.root3  = (const float*)d_in[19]; prm.cb3    = (const float*)d_in[20];
  prm.fc1w   = (const float*)d_in[21]; prm.fc1b   = (const float*)d_in[22];
  prm.fc2w   = (const float*)d_in[23]; prm.fc2b   = (const float*)d_in[24];
  prm.fc3w   = (const float*)d_in[25]; prm.fc3b   = (const float*)d_in[26];
  prm.out = (float*)d_out;

  prm.N = in_sizes[0] / 4;
  prm.E = in_sizes[1] / 2;
  prm.Epad = (prm.E + 63) & ~63;

  prm.ef2b = (short*)d_ws;
  prm.ef3b = prm.ef2b + (size_t)prm.Epad*64;
  prm.w2p2 = prm.ef3b + (size_t)prm.Epad*64;
  prm.w2p3 = prm.w2p2 + 8*4*2*512;
  prm.a1   = (float*)(prm.w2p3 + 64*8*2*512);
  prm.a2   = prm.a1 + (size_t)prm.N*8;
  prm.a3   = prm.a2 + (size_t)prm.N*64;
  prm.g    = prm.a3 + (size_t)prm.N*128;

  int maxB = 0;
  hipOccupancyMaxActiveBlocksPerMultiprocessor(&maxB, mega, 256, 0);
  int grid = maxB * 256;             // 256 CUs on MI355X
  if (grid > 1024) grid = 1024;
  if (grid < 256)  grid = 256;

  void* args[] = { &prm };
  hipLaunchCooperativeKernel((const void*)mega, dim3(grid), dim3(256), args, 0, stream);
}

// Round 8
// 244.500 us; speedup vs baseline: 2.9926x; 2.9926x over previous
//
#include <hip/hip_runtime.h>
#include <hip/hip_bf16.h>

typedef __attribute__((ext_vector_type(8))) short short8;
typedef __attribute__((ext_vector_type(4))) float floatx4;
typedef __attribute__((ext_vector_type(2))) float float2v;

__device__ __forceinline__ float leaky(float v){ return v > 0.f ? v : 0.1f*v; }
__device__ __forceinline__ void atomAdd(float* p, float v){ unsafeAtomicAdd(p, v); }
__device__ __forceinline__ short f2bf(float f){
  __hip_bfloat16 h = __float2bfloat16(f);
  return *reinterpret_cast<short*>(&h);
}

struct P {
  const float *x; const int *ei; const int *batch;
  const float *en1_w1,*en1_b1,*en1_w2,*en1_b2;
  const float *en2_w1,*en2_b1,*en2_w2,*en2_b2;
  const float *en3_w1,*en3_b1,*en3_w2,*en3_b2;
  const float *root1,*cb1,*root2,*cb2,*root3,*cb3;
  const float *fc1w,*fc1b,*fc2w,*fc2b,*fc3w,*fc3b;
  short *ef2b,*ef3b,*w2p2,*w2p3;
  float *a1,*a2,*a3,*g,*out;
  int N,E,Epad;
};

// Dispatch 2 (multi-role): blocks [0, Epad/4) do edge-features + conv1;
// blocks [Epad/4, Epad/4+272) pack both w2 matrices into MFMA B-fragment order.
__global__ __launch_bounds__(256) void fused0(P p){
  int bid = blockIdx.x, tid = threadIdx.x;
  int nEf = p.Epad/4;
  if (bid < nEf){
    __shared__ float sm[4][64];
    int id = bid*256 + tid;
    int e = id >> 6, j = id & 63;
    float v1 = 0.f;
    if (e >= p.E){
      p.ef2b[id] = 0; p.ef3b[id] = 0;
    } else {
      int s = p.ei[e], d = p.ei[p.E+e];
      float4 xs = *reinterpret_cast<const float4*>(p.x + (size_t)s*4);
      float4 xd = *reinterpret_cast<const float4*>(p.x + (size_t)d*4);
      float d0 = xd.y - xs.y, d1 = xd.z - xs.z, d2 = xd.w - xs.w;
      v1 = leaky(d0*p.en1_w1[j] + d1*p.en1_w1[64+j] + d2*p.en1_w1[128+j] + p.en1_b1[j]);
      p.ef2b[id] = f2bf(leaky(d0*p.en2_w1[j] + d1*p.en2_w1[64+j] + d2*p.en2_w1[128+j] + p.en2_b1[j]));
      p.ef3b[id] = f2bf(leaky(d0*p.en3_w1[j] + d1*p.en3_w1[64+j] + d2*p.en3_w1[128+j] + p.en3_b1[j]));
    }
    sm[tid >> 6][j] = v1;
    __syncthreads();
    if (tid < 32){
      int le = tid >> 3, o = tid & 7;
      int ge = bid*4 + le;
      if (ge < p.E){
        int s = p.ei[ge], d = p.ei[p.E+ge];
        float z[4];
        #pragma unroll
        for (int i=0;i<4;i++) z[i] = p.en1_b2[i*8+o];
        for (int k=0;k<64;k++){
          float a = sm[le][k];
          #pragma unroll
          for (int i=0;i<4;i++) z[i] += a*p.en1_w2[k*32 + i*8 + o];
        }
        float4 xv = *reinterpret_cast<const float4*>(p.x + (size_t)s*4);
        float msg = xv.x*leaky(z[0]) + xv.y*leaky(z[1]) + xv.z*leaky(z[2]) + xv.w*leaky(z[3]);
        atomAdd(&p.a1[(size_t)d*8 + o], msg);
      }
    }
  } else {
    int pb = bid - nEf;                 // 0..271
    int lane = tid & 63;
    int c = pb*4 + (tid >> 6);          // 0..1087
    const float* w2; short* dst; int ICOC, OT, cc;
    if (c < 64){ w2 = p.en2_w2; dst = p.w2p2; ICOC = 512;  OT = 4; cc = c; }
    else       { w2 = p.en3_w2; dst = p.w2p3; ICOC = 8192; OT = 8; cc = c - 64; }
    int kh = cc & 1, rem = cc >> 1, otg = rem % OT, i = rem / OT;
    int n = lane & 15, q = lane >> 4;
    short o8[8];
    #pragma unroll
    for (int j=0;j<8;j++){
      int k = kh*32 + q*8 + j;
      o8[j] = f2bf(w2[(size_t)k*ICOC + i*(OT*16) + otg*16 + n]);
    }
    *reinterpret_cast<short8*>(dst + (size_t)cc*512 + lane*8) = *reinterpret_cast<short8*>(o8);
  }
}

// conv2 with node1 inlined into staging. 32 edges/block; MB=2, OT=4, WOT=1, ICB=8.
__global__ __launch_bounds__(256) void conv2k(P p){
  __shared__ float hsT[8][32];
  __shared__ int sdst[32];
  int tid = threadIdx.x;
  int eb = blockIdx.x*32;
  int E = p.E;
  {
    int e = tid & 31, i = tid >> 5;
    int ge = eb + e;
    bool valid = ge < E;
    int src = valid ? p.ei[ge] : 0;
    float hv = 0.f;
    if (valid){
      float4 xv = *reinterpret_cast<const float4*>(p.x + (size_t)src*4);
      float v = p.a1[(size_t)src*8 + i] + p.cb1[i]
              + xv.x*p.root1[i] + xv.y*p.root1[8+i] + xv.z*p.root1[16+i] + xv.w*p.root1[24+i];
      hv = leaky(v);
    }
    hsT[i][e] = hv;
    if (tid < 32) sdst[tid] = (eb + tid < E) ? p.ei[E + eb + tid] : -1;
  }
  __syncthreads();

  int lane = tid & 63, wv = tid >> 6;
  int n = lane & 15, quad = lane >> 4;
  int o0 = wv*16;
  short8 A[2][2];
  #pragma unroll
  for (int m=0;m<2;m++)
    #pragma unroll
    for (int kh=0;kh<2;kh++)
      A[m][kh] = *reinterpret_cast<const short8*>(p.ef2b + (size_t)(eb + m*16 + n)*64 + kh*32 + quad*8);

  float2v msg[2][2];
  msg[0][0]=(float2v){0.f,0.f}; msg[0][1]=(float2v){0.f,0.f};
  msg[1][0]=(float2v){0.f,0.f}; msg[1][1]=(float2v){0.f,0.f};

  auto loadB = [&](int ii, short8 (&Bt)[2], float &bz){
    int ig = (ii < 8) ? ii : 7;
    #pragma unroll
    for (int kh=0;kh<2;kh++)
      Bt[kh] = *reinterpret_cast<const short8*>(p.w2p2 + ((size_t)((ig*4 + wv)*2 + kh) << 9) + lane*8);
    bz = p.en2_b2[ig*64 + o0 + n];
  };
  auto compute = [&](int ii, short8 (&Bt)[2], float bz){
    #pragma unroll
    for (int m=0;m<2;m++){
      float4 hv = *reinterpret_cast<const float4*>(&hsT[ii][m*16 + quad*4]);
      float2v hvl = {hv.x, hv.y}, hvh = {hv.z, hv.w};
      floatx4 z = {bz, bz, bz, bz};
      z = __builtin_amdgcn_mfma_f32_16x16x32_bf16(A[m][0], Bt[0], z, 0, 0, 0);
      z = __builtin_amdgcn_mfma_f32_16x16x32_bf16(A[m][1], Bt[1], z, 0, 0, 0);
      float2v zl = {z[0], z[1]}, zh = {z[2], z[3]};
      float2v ll = __builtin_elementwise_max(zl, zl*0.1f);
      float2v lh = __builtin_elementwise_max(zh, zh*0.1f);
      msg[m][0] += hvl*ll;
      msg[m][1] += hvh*lh;
    }
  };

  short8 B0[2], B1[2]; float bz0, bz1;
  loadB(0, B0, bz0);
  #pragma unroll 2
  for (int i=0;i<8;i+=2){
    loadB(i+1, B1, bz1);
    compute(i, B0, bz0);
    loadB(i+2, B0, bz0);
    compute(i+1, B1, bz1);
  }

  #pragma unroll
  for (int m=0;m<2;m++)
    #pragma unroll
    for (int r=0;r<4;r++){
      int d = sdst[m*16 + quad*4 + r];
      if (d >= 0) atomAdd(&p.a2[(size_t)d*64 + o0 + n], msg[m][r>>1][r&1]);
    }
}

// conv3 with node1+node2 recomputed in staging. 64 edges/block, 2-way ic-split.
// MB=4, OT=8, WOT=2, ICB=32.
__global__ __launch_bounds__(256) void conv3k(P p){
  __shared__ float hsT[32][64];
  __shared__ int sdst[64];
  __shared__ float r2s[512];
  __shared__ float cb2s[64];
  int tid = threadIdx.x;
  int bi = blockIdx.x;
  int eb = (bi >> 1)*64;
  int i0 = (bi & 1)*32;
  int E = p.E;

  r2s[tid]     = p.root2[tid];
  r2s[256+tid] = p.root2[256+tid];
  if (tid < 64) cb2s[tid] = p.cb2[tid];
  if (tid < 64) sdst[tid] = (eb + tid < E) ? p.ei[E + eb + tid] : -1;

  int e = tid & 63, c = tid >> 6;       // c in [0,4): 8 channels each
  int ge = eb + e;
  bool valid = ge < E;
  int src = valid ? p.ei[ge] : 0;
  float h1[8];
  {
    float4 xv  = *reinterpret_cast<const float4*>(p.x  + (size_t)src*4);
    float4 a1l = *reinterpret_cast<const float4*>(p.a1 + (size_t)src*8);
    float4 a1h = *reinterpret_cast<const float4*>(p.a1 + (size_t)src*8 + 4);
    float a1v[8] = {a1l.x,a1l.y,a1l.z,a1l.w,a1h.x,a1h.y,a1h.z,a1h.w};
    #pragma unroll
    for (int k=0;k<8;k++){
      float v = a1v[k] + p.cb1[k] + xv.x*p.root1[k] + xv.y*p.root1[8+k]
              + xv.z*p.root1[16+k] + xv.w*p.root1[24+k];
      h1[k] = leaky(v);
    }
  }
  __syncthreads();   // r2s/cb2s ready
  {
    int ib = i0 + c*8;
    float4 acc0 = *reinterpret_cast<const float4*>(p.a2 + (size_t)src*64 + ib);
    float4 acc1 = *reinterpret_cast<const float4*>(p.a2 + (size_t)src*64 + ib + 4);
    float4 cb0 = *reinterpret_cast<const float4*>(&cb2s[ib]);
    float4 cb1v = *reinterpret_cast<const float4*>(&cb2s[ib+4]);
    acc0.x+=cb0.x; acc0.y+=cb0.y; acc0.z+=cb0.z; acc0.w+=cb0.w;
    acc1.x+=cb1v.x; acc1.y+=cb1v.y; acc1.z+=cb1v.z; acc1.w+=cb1v.w;
    #pragma unroll
    for (int k=0;k<8;k++){
      float hk = h1[k];
      float4 r0 = *reinterpret_cast<const float4*>(&r2s[k*64+ib]);
      float4 r1 = *reinterpret_cast<const float4*>(&r2s[k*64+ib+4]);
      acc0.x += hk*r0.x; acc0.y += hk*r0.y; acc0.z += hk*r0.z; acc0.w += hk*r0.w;
      acc1.x += hk*r1.x; acc1.y += hk*r1.y; acc1.z += hk*r1.z; acc1.w += hk*r1.w;
    }
    hsT[c*8+0][e] = valid ? leaky(acc0.x) : 0.f;
    hsT[c*8+1][e] = valid ? leaky(acc0.y) : 0.f;
    hsT[c*8+2][e] = valid ? leaky(acc0.z) : 0.f;
    hsT[c*8+3][e] = valid ? leaky(acc0.w) : 0.f;
    hsT[c*8+4][e] = valid ? leaky(acc1.x) : 0.f;
    hsT[c*8+5][e] = valid ? leaky(acc1.y) : 0.f;
    hsT[c*8+6][e] = valid ? leaky(acc1.z) : 0.f;
    hsT[c*8+7][e] = valid ? leaky(acc1.w) : 0.f;
  }
  __syncthreads();

  int lane = tid & 63, wv = tid >> 6;
  int n = lane & 15, quad = lane >> 4;
  int o0 = wv*32;
  short8 A[4][2];
  #pragma unroll
  for (int m=0;m<4;m++)
    #pragma unroll
    for (int kh=0;kh<2;kh++)
      A[m][kh] = *reinterpret_cast<const short8*>(p.ef3b + (size_t)(eb + m*16 + n)*64 + kh*32 + quad*8);

  float2v msg[4][2][2];
  #pragma unroll
  for (int m=0;m<4;m++)
    #pragma unroll
    for (int t=0;t<2;t++){
      msg[m][t][0]=(float2v){0.f,0.f}; msg[m][t][1]=(float2v){0.f,0.f};
    }

  auto loadB = [&](int ii, short8 (&Bt)[2][2], float (&bzt)[2]){
    int il = (ii < 32) ? ii : 31;
    int ig = i0 + il;
    #pragma unroll
    for (int t=0;t<2;t++){
      int otg = wv*2 + t;
      #pragma unroll
      for (int kh=0;kh<2;kh++)
        Bt[t][kh] = *reinterpret_cast<const short8*>(p.w2p3 + ((size_t)((ig*8 + otg)*2 + kh) << 9) + lane*8);
      bzt[t] = p.en3_b2[ig*128 + o0 + t*16 + n];
    }
  };
  auto compute = [&](int ii, short8 (&Bt)[2][2], float (&bzt)[2]){
    #pragma unroll
    for (int m=0;m<4;m++){
      float4 hv = *reinterpret_cast<const float4*>(&hsT[ii][m*16 + quad*4]);
      float2v hvl = {hv.x, hv.y}, hvh = {hv.z, hv.w};
      #pragma unroll
      for (int t=0;t<2;t++){
        floatx4 z = {bzt[t], bzt[t], bzt[t], bzt[t]};
        z = __builtin_amdgcn_mfma_f32_16x16x32_bf16(A[m][0], Bt[t][0], z, 0, 0, 0);
        z = __builtin_amdgcn_mfma_f32_16x16x32_bf16(A[m][1], Bt[t][1], z, 0, 0, 0);
        float2v zl = {z[0], z[1]}, zh = {z[2], z[3]};
        float2v ll = __builtin_elementwise_max(zl, zl*0.1f);
        float2v lh = __builtin_elementwise_max(zh, zh*0.1f);
        msg[m][t][0] += hvl*ll;
        msg[m][t][1] += hvh*lh;
      }
    }
  };

  short8 B0[2][2], B1[2][2];
  float bz0[2], bz1[2];
  loadB(0, B0, bz0);
  #pragma unroll 2
  for (int i=0;i<32;i+=2){
    loadB(i+1, B1, bz1);
    compute(i, B0, bz0);
    loadB(i+2, B0, bz0);
    compute(i+1, B1, bz1);
  }

  #pragma unroll
  for (int m=0;m<4;m++)
    #pragma unroll
    for (int r=0;r<4;r++){
      int d = sdst[m*16 + quad*4 + r];
      if (d >= 0){
        #pragma unroll
        for (int t=0;t<2;t++)
          atomAdd(&p.a3[(size_t)d*128 + o0 + t*16 + n], msg[m][t][r>>1][r&1]);
      }
    }
}

// node3 + pool with h2 recomputed per node (a3 = raw conv3 agg).
__global__ __launch_bounds__(256) void npk(P p){
  __shared__ float r3s[8192];
  __shared__ float r2s[512];
  __shared__ float cb2s[64];
  __shared__ float hrow[16][64];
  int tid = threadIdx.x;
  int N = p.N;
  for (int r=tid; r<2048; r+=256)
    reinterpret_cast<float4*>(r3s)[r] = reinterpret_cast<const float4*>(p.root3)[r];
  r2s[tid]     = p.root2[tid];
  r2s[256+tid] = p.root2[256+tid];
  if (tid < 64) cb2s[tid] = p.cb2[tid];
  __syncthreads();

  int n0 = blockIdx.x*16;
  {
    int nl = tid >> 4, c0 = (tid & 15)*4;
    int n = n0 + nl;
    int nn = (n < N) ? n : 0;
    float4 xv  = *reinterpret_cast<const float4*>(p.x  + (size_t)nn*4);
    float4 a1l = *reinterpret_cast<const float4*>(p.a1 + (size_t)nn*8);
    float4 a1h = *reinterpret_cast<const float4*>(p.a1 + (size_t)nn*8 + 4);
    float a1v[8] = {a1l.x,a1l.y,a1l.z,a1l.w,a1h.x,a1h.y,a1h.z,a1h.w};
    float h1[8];
    #pragma unroll
    for (int k=0;k<8;k++){
      float v = a1v[k] + p.cb1[k] + xv.x*p.root1[k] + xv.y*p.root1[8+k]
              + xv.z*p.root1[16+k] + xv.w*p.root1[24+k];
      h1[k] = leaky(v);
    }
    float4 acc = *reinterpret_cast<const float4*>(p.a2 + (size_t)nn*64 + c0);
    float4 cbv = *reinterpret_cast<const float4*>(&cb2s[c0]);
    acc.x+=cbv.x; acc.y+=cbv.y; acc.z+=cbv.z; acc.w+=cbv.w;
    #pragma unroll
    for (int k=0;k<8;k++){
      float hk = h1[k];
      float4 rv = *reinterpret_cast<const float4*>(&r2s[k*64+c0]);
      acc.x += hk*rv.x; acc.y += hk*rv.y; acc.z += hk*rv.z; acc.w += hk*rv.w;
    }
    hrow[nl][c0+0] = leaky(acc.x);
    hrow[nl][c0+1] = leaky(acc.y);
    hrow[nl][c0+2] = leaky(acc.z);
    hrow[nl][c0+3] = leaky(acc.w);
  }
  __syncthreads();

  int o = tid & 127, np_ = tid >> 7;
  float acc = 0.f; int cur = -1;
  for (int rep=0; rep<8; rep++){
    int nl = rep*2 + np_; int n = n0 + nl;
    if (n >= N) break;
    int b = p.batch[n];
    if (b != cur){ if (cur >= 0) atomAdd(&p.g[cur*128+o], acc); acc = 0.f; cur = b; }
    float v = p.a3[(size_t)n*128 + o] + p.cb3[o];
    #pragma unroll 16
    for (int i=0;i<64;i++) v += hrow[nl][i]*r3s[i*128+o];
    acc += leaky(v);
  }
  if (cur >= 0) atomAdd(&p.g[cur*128+o], acc);
}

// readout MLP: one block per graph
__global__ void head_kernel(P p){
  __shared__ float s1[128], s2[128];
  int gi = blockIdx.x, t = threadIdx.x;
  s1[t] = p.g[gi*128+t];
  __syncthreads();
  float v = p.fc1b[t];
  for (int i=0;i<128;i++) v += s1[i]*p.fc1w[i*128+t];
  s2[t] = leaky(v);
  __syncthreads();
  if (t < 64){
    float v2 = p.fc2b[t];
    for (int i=0;i<128;i++) v2 += s2[i]*p.fc2w[i*64+t];
    s1[t] = leaky(v2);
  }
  __syncthreads();
  if (t == 0){
    float v3 = p.fc3b[0];
    for (int i=0;i<64;i++) v3 += s1[i]*p.fc3w[i];
    p.out[gi] = v3;
  }
}

extern "C" void kernel_launch(void* const* d_in, const int* in_sizes, int n_in,
                              void* d_out, int out_size, void* d_ws, size_t ws_size,
                              hipStream_t stream) {
  P p;
  p.x      = (const float*)d_in[0];
  p.ei     = (const int*)  d_in[1];
  p.batch  = (const int*)  d_in[2];
  p.en1_w1 = (const float*)d_in[3];  p.en1_b1 = (const float*)d_in[4];
  p.en1_w2 = (const float*)d_in[5];  p.en1_b2 = (const float*)d_in[6];
  p.en2_w1 = (const float*)d_in[7];  p.en2_b1 = (const float*)d_in[8];
  p.en2_w2 = (const float*)d_in[9];  p.en2_b2 = (const float*)d_in[10];
  p.en3_w1 = (const float*)d_in[11]; p.en3_b1 = (const float*)d_in[12];
  p.en3_w2 = (const float*)d_in[13]; p.en3_b2 = (const float*)d_in[14];
  p.root1  = (const float*)d_in[15]; p.cb1    = (const float*)d_in[16];
  p.root2  = (const float*)d_in[17]; p.cb2    = (const float*)d_in[18];
  p.root3  = (const float*)d_in[19]; p.cb3    = (const float*)d_in[20];
  p.fc1w   = (const float*)d_in[21]; p.fc1b   = (const float*)d_in[22];
  p.fc2w   = (const float*)d_in[23]; p.fc2b   = (const float*)d_in[24];
  p.fc3w   = (const float*)d_in[25]; p.fc3b   = (const float*)d_in[26];
  p.out = (float*)d_out;

  p.N = in_sizes[0] / 4;
  p.E = in_sizes[1] / 2;
  p.Epad = (p.E + 63) & ~63;

  p.ef2b = (short*)d_ws;
  p.ef3b = p.ef2b + (size_t)p.Epad*64;
  p.w2p2 = p.ef3b + (size_t)p.Epad*64;
  p.w2p3 = p.w2p2 + 8*4*2*512;
  p.a1   = (float*)(p.w2p3 + 64*8*2*512);
  p.a2   = p.a1 + (size_t)p.N*8;
  p.a3   = p.a2 + (size_t)p.N*64;
  p.g    = p.a3 + (size_t)p.N*128;

  size_t zero_bytes = ((size_t)p.N*(8+64+128) + (size_t)32*128) * sizeof(float);
  hipMemsetAsync(p.a1, 0, zero_bytes, stream);

  fused0<<<p.Epad/4 + 272, 256, 0, stream>>>(p);
  conv2k<<<p.Epad/32, 256, 0, stream>>>(p);
  conv3k<<<(p.Epad/64)*2, 256, 0, stream>>>(p);
  npk<<<(p.N + 15)/16, 256, 0, stream>>>(p);
  head_kernel<<<32, 128, 0, stream>>>(p);
}